// Round 1
// baseline (47.597 us; speedup 1.0000x reference)
//
#include <hip/hip_runtime.h>
#include <hip/hip_bf16.h>
#include <math.h>

// out[p][i][j] = sigmoid(C * D / 512), p in [0,64), i,j in [0,256)
//   D = sum_k sqrt((x_k - i)^2 + (y_k - j)^2)    (x = col-of-roll = polygons[...,1]*256,
//                                                 y = polygons[...,0]*256; pts=(i,j))
//   C = +1 if even-odd crossing parity says inside, else -1
// Crossing test replicated EXACTLY as the float32 reference does it
// (exact *256 scale, IEEE subs, IEEE divide) so no boundary pixel flips.

__global__ __launch_bounds__(256)
void raster_kernel(const float* __restrict__ poly, float* __restrict__ out) {
    int gid = blockIdx.x * blockDim.x + threadIdx.x;
    int p   = gid >> 16;          // polygon index 0..63
    int pix = gid & 65535;
    float px = (float)(pix >> 8);   // row i  -> pts[:,0]
    float py = (float)(pix & 255);  // col j  -> pts[:,1]

    // Load 8 vertices (16 floats) as 4x float4; all threads of the block share
    // one polygon so these broadcast from L1.
    const float4* v4 = (const float4*)(poly + (size_t)p * 16);
    float4 q0 = v4[0], q1 = v4[1], q2 = v4[2], q3 = v4[3];

    float x[8], y[8];
    // roll(...,1,axis=-1): polys[...,0] = polygons[...,1]*256 ; polys[...,1] = polygons[...,0]*256
    // _inside uses x = polys[...,0], y = polys[...,1]; D is symmetric so same pairing works.
    y[0] = q0.x * 256.0f; x[0] = q0.y * 256.0f;
    y[1] = q0.z * 256.0f; x[1] = q0.w * 256.0f;
    y[2] = q1.x * 256.0f; x[2] = q1.y * 256.0f;
    y[3] = q1.z * 256.0f; x[3] = q1.w * 256.0f;
    y[4] = q2.x * 256.0f; x[4] = q2.y * 256.0f;
    y[5] = q2.z * 256.0f; x[5] = q2.w * 256.0f;
    y[6] = q3.x * 256.0f; x[6] = q3.y * 256.0f;
    y[7] = q3.z * 256.0f; x[7] = q3.w * 256.0f;
    // NOTE on axis naming: in the reference, polys[...,0] pairs with pts[...,0]=i=px
    // and polys[...,1] pairs with pts[...,1]=j=py. Here x[] holds polys[...,0]
    // (compared against px) and y[] holds polys[...,1] (compared against py).
    // polys[...,0] = rolled coord 0 = polygons[...,1]*256  -> that is x[] above? Check:
    //   q0.x = polygons[p][0][0]; q0.y = polygons[p][0][1]
    //   rolled: polys[...,0] = polygons[...,1], polys[...,1] = polygons[...,0]
    //   so x[k] (=polys[...,0]) = polygons[...,1]*256 = q.y*256  ✓ (as written)
    //      y[k] (=polys[...,1]) = polygons[...,0]*256 = q.x*256  ✓

    float D = 0.0f;
    int crossings = 0;
    #pragma unroll
    for (int k = 0; k < 8; ++k) {
        float dx = x[k] - px;
        float dy = y[k] - py;
        D += sqrtf(dx * dx + dy * dy);

        int kn = (k + 1) & 7;
        bool cond = (y[k] > py) != (y[kn] > py);
        // Reference: denom = cond ? (yn - y) : 1.0 ; xint = (xn-x)*(py-y)/denom + x
        float denom = cond ? (y[kn] - y[k]) : 1.0f;
        float xint  = (x[kn] - x[k]) * (py - y[k]) / denom + x[k];
        crossings += (cond && (px < xint)) ? 1 : 0;
    }

    float C = (crossings & 1) ? 1.0f : -1.0f;
    float z = C * D * (1.0f / 512.0f);       // /512 is exact (power of two)
    // sigmoid; smooth path, fast exp is fine for the 1.9e-2 threshold
    out[gid] = 1.0f / (1.0f + __expf(-z));
}

extern "C" void kernel_launch(void* const* d_in, const int* in_sizes, int n_in,
                              void* d_out, int out_size, void* d_ws, size_t ws_size,
                              hipStream_t stream) {
    const float* poly = (const float*)d_in[0];
    float* out = (float*)d_out;
    int threads = 256;
    int blocks = (out_size + threads - 1) / threads;   // 64*65536/256 = 16384
    raster_kernel<<<blocks, threads, 0, stream>>>(poly, out);
}

// Round 2
// 18.133 us; speedup vs baseline: 2.6249x; 2.6249x over previous
//
#include <hip/hip_runtime.h>
#include <hip/hip_bf16.h>
#include <math.h>

// out[p][i][j] = sigmoid(C * D / 512), p<64, i,j<256
//   x[k] = polygons[p][k][1]*256 (compared against px=i)
//   y[k] = polygons[p][k][0]*256 (compared against py=j)
// Crossing structure: xint,cond depend only on (p,k,j). Kernel 1 builds a
// 256-bit parity mask over rows i per (p,j) using EXACT reference IEEE math;
// kernel 2 does the smooth distance field + sigmoid with fast approximations.

#define LOAD_VERTS(poly_p)                                         \
    const float4* v4 = (const float4*)(poly_p);                    \
    float4 q0 = v4[0], q1 = v4[1], q2 = v4[2], q3 = v4[3];         \
    float x[8], y[8];                                              \
    y[0] = q0.x * 256.0f; x[0] = q0.y * 256.0f;                    \
    y[1] = q0.z * 256.0f; x[1] = q0.w * 256.0f;                    \
    y[2] = q1.x * 256.0f; x[2] = q1.y * 256.0f;                    \
    y[3] = q1.z * 256.0f; x[3] = q1.w * 256.0f;                    \
    y[4] = q2.x * 256.0f; x[4] = q2.y * 256.0f;                    \
    y[5] = q2.z * 256.0f; x[5] = q2.w * 256.0f;                    \
    y[6] = q3.x * 256.0f; x[6] = q3.y * 256.0f;                    \
    y[7] = q3.z * 256.0f; x[7] = q3.w * 256.0f;

// ---------------- Kernel 1: parity masks --------------------------------
// thread (p=blockIdx.x, j=threadIdx.x) -> 8 u32 words; word w covers rows
// i in [32w,32w+32). Stored ws[(p*8+w)*256 + j] so kernel 2 lanes (j) coalesce.
__global__ __launch_bounds__(256)
void mask_kernel(const float* __restrict__ poly, unsigned int* __restrict__ ws) {
    int p = blockIdx.x;
    int j = threadIdx.x;
    float py = (float)j;
    LOAD_VERTS(poly + (size_t)p * 16)

    unsigned int mask[8] = {0,0,0,0,0,0,0,0};
    #pragma unroll
    for (int k = 0; k < 8; ++k) {
        int kn = (k + 1) & 7;
        bool cond = (y[k] > py) != (y[kn] > py);
        if (cond) {
            // EXACT reference arithmetic (IEEE ops, same order). denom = yn-y
            // is nonzero whenever cond is true, so no NaN possible.
            float denom = y[kn] - y[k];
            float xint  = (x[kn] - x[k]) * (py - y[k]) / denom + x[k];
            // m = #{ integer i in [0,256) : (float)i < xint }  (exact)
            int m;
            if (!(xint > 0.0f))       m = 0;
            else if (xint > 255.0f)   m = 256;
            else                      m = (int)ceilf(xint);   // ceilf exact
            #pragma unroll
            for (int w = 0; w < 8; ++w) {
                int r = m - (w << 5);
                unsigned int ones = (r <= 0) ? 0u
                                  : (r >= 32) ? 0xffffffffu
                                  : ((1u << r) - 1u);
                mask[w] ^= ones;
            }
        }
    }
    #pragma unroll
    for (int w = 0; w < 8; ++w)
        ws[((p << 3) + w << 8) + j] = mask[w];
}

// ---------------- Kernel 2: distance field + sigmoid --------------------
// block = (p, i): p = blockIdx>>8, i = blockIdx&255 (both wave-uniform);
// lane = j. Mask word read is coalesced; bit shift amount (i&31) is scalar.
__global__ __launch_bounds__(256)
void raster_kernel(const float* __restrict__ poly,
                   const unsigned int* __restrict__ ws,
                   float* __restrict__ out) {
    int bid = blockIdx.x;
    int p = bid >> 8;
    int i = bid & 255;
    int j = threadIdx.x;
    float px = (float)i;
    float py = (float)j;
    LOAD_VERTS(poly + (size_t)p * 16)

    unsigned int word = ws[((p << 3) + (i >> 5) << 8) + j];
    int inside = (word >> (i & 31)) & 1;

    float D = 0.0f;
    #pragma unroll
    for (int k = 0; k < 8; ++k) {
        float dx = x[k] - px;
        float dy = y[k] - py;
        // approx sqrt (~1 ulp): D tolerance is ~39 units, vastly safe
        D += __builtin_amdgcn_sqrtf(fmaf(dy, dy, dx * dx));
    }

    float C = inside ? 1.0f : -1.0f;
    float z = C * D * (1.0f / 512.0f);
    float e = __expf(-z);                       // v_exp_f32 path
    out[(size_t)bid * 256 + j] = __builtin_amdgcn_rcpf(1.0f + e);
}

// ---------------- Fallback (round-1 kernel) if ws too small -------------
__global__ __launch_bounds__(256)
void raster_fallback(const float* __restrict__ poly, float* __restrict__ out) {
    int gid = blockIdx.x * blockDim.x + threadIdx.x;
    int p   = gid >> 16;
    int pix = gid & 65535;
    float px = (float)(pix >> 8);
    float py = (float)(pix & 255);
    LOAD_VERTS(poly + (size_t)p * 16)

    float D = 0.0f;
    int crossings = 0;
    #pragma unroll
    for (int k = 0; k < 8; ++k) {
        float dx = x[k] - px;
        float dy = y[k] - py;
        D += __builtin_amdgcn_sqrtf(fmaf(dy, dy, dx * dx));
        int kn = (k + 1) & 7;
        bool cond = (y[k] > py) != (y[kn] > py);
        float denom = cond ? (y[kn] - y[k]) : 1.0f;
        float xint  = (x[kn] - x[k]) * (py - y[k]) / denom + x[k];
        crossings += (cond && (px < xint)) ? 1 : 0;
    }
    float C = (crossings & 1) ? 1.0f : -1.0f;
    float z = C * D * (1.0f / 512.0f);
    float e = __expf(-z);
    out[gid] = __builtin_amdgcn_rcpf(1.0f + e);
}

extern "C" void kernel_launch(void* const* d_in, const int* in_sizes, int n_in,
                              void* d_out, int out_size, void* d_ws, size_t ws_size,
                              hipStream_t stream) {
    const float* poly = (const float*)d_in[0];
    float* out = (float*)d_out;
    if (ws_size >= (size_t)(64 * 8 * 256 * 4)) {
        unsigned int* ws = (unsigned int*)d_ws;
        mask_kernel<<<64, 256, 0, stream>>>(poly, ws);
        raster_kernel<<<16384, 256, 0, stream>>>(poly, ws, out);
    } else {
        raster_fallback<<<16384, 256, 0, stream>>>(poly, out);
    }
}

// Round 3
// 15.594 us; speedup vs baseline: 3.0522x; 1.1628x over previous
//
#include <hip/hip_runtime.h>
#include <hip/hip_bf16.h>
#include <math.h>

// out[p][i][j] = sigmoid(C * D / 512), p<64, i,j<256
//   x[k] = polygons[p][k][1]*256 (compared against px=i)
//   y[k] = polygons[p][k][0]*256 (compared against py=j)
//
// Single fused kernel. Block = (p, 16-row stripe), thread = column j.
// Each thread builds a 16-bit even-odd parity mask for its 16 rows using
// EXACT reference float32 arithmetic (IEEE divide, same op order) so no
// boundary pixel can flip, then evaluates the smooth distance field with
// fast approximations (v_sqrt/v_exp/v_rcp; tolerance is huge: sigmoid slope
// <= 0.25/512 per unit D, threshold 0.019 => ~39 units of D slack).

#define LOAD_VERTS(poly_p)                                         \
    const float4* v4 = (const float4*)(poly_p);                    \
    float4 q0 = v4[0], q1 = v4[1], q2 = v4[2], q3 = v4[3];         \
    float x[8], y[8];                                              \
    y[0] = q0.x * 256.0f; x[0] = q0.y * 256.0f;                    \
    y[1] = q0.z * 256.0f; x[1] = q0.w * 256.0f;                    \
    y[2] = q1.x * 256.0f; x[2] = q1.y * 256.0f;                    \
    y[3] = q1.z * 256.0f; x[3] = q1.w * 256.0f;                    \
    y[4] = q2.x * 256.0f; x[4] = q2.y * 256.0f;                    \
    y[5] = q2.z * 256.0f; x[5] = q2.w * 256.0f;                    \
    y[6] = q3.x * 256.0f; x[6] = q3.y * 256.0f;                    \
    y[7] = q3.z * 256.0f; x[7] = q3.w * 256.0f;

__global__ __launch_bounds__(256)
void raster_fused(const float* __restrict__ poly, float* __restrict__ out) {
    int bid = blockIdx.x;
    int p  = bid >> 4;            // polygon
    int i0 = (bid & 15) << 4;     // stripe start row
    int j  = threadIdx.x;         // column
    float py = (float)j;
    LOAD_VERTS(poly + (size_t)p * 16)

    // ---- exact parity mask for rows [i0, i0+16) ----
    unsigned int mask = 0;
    #pragma unroll
    for (int k = 0; k < 8; ++k) {
        int kn = (k + 1) & 7;
        bool cond = (y[k] > py) != (y[kn] > py);
        if (cond) {   // divergent branch: waves whose 64-col window misses the
                      // edge's y-span skip the whole divide
            float denom = y[kn] - y[k];                       // nonzero when cond
            float xint  = (x[kn] - x[k]) * (py - y[k]) / denom + x[k]; // IEEE, ref order
            // m = #{ integer i in [0,256) : (float)i < xint }   (exact)
            int m;
            if (!(xint > 0.0f))       m = 0;
            else if (xint > 255.0f)   m = 256;
            else                      m = (int)ceilf(xint);
            int r = m - i0;         // rows i0..i0+r-1 of this stripe cross
            unsigned int ones = (r <= 0) ? 0u
                              : (r >= 16) ? 0xffffu
                              : ((1u << r) - 1u);
            mask ^= ones;
        }
    }

    // ---- smooth path: D + sigmoid over the 16 rows ----
    float dy2[8], xr[8];
    #pragma unroll
    for (int k = 0; k < 8; ++k) {
        float dy = y[k] - py;
        dy2[k] = dy * dy;
        xr[k]  = x[k] - (float)i0;
    }

    float* op = out + ((((size_t)p << 8) + i0) << 8) + j;
    #pragma unroll 4
    for (int r = 0; r < 16; ++r) {
        float rf = (float)r;
        float D = 0.0f;
        #pragma unroll
        for (int k = 0; k < 8; ++k) {
            float dx = xr[k] - rf;
            D += __builtin_amdgcn_sqrtf(fmaf(dx, dx, dy2[k]));
        }
        float C = ((mask >> r) & 1) ? 1.0f : -1.0f;
        float z = C * D * (1.0f / 512.0f);
        float e = __expf(-z);
        op[(size_t)r << 8] = __builtin_amdgcn_rcpf(1.0f + e);
    }
}

extern "C" void kernel_launch(void* const* d_in, const int* in_sizes, int n_in,
                              void* d_out, int out_size, void* d_ws, size_t ws_size,
                              hipStream_t stream) {
    const float* poly = (const float*)d_in[0];
    float* out = (float*)d_out;
    // 64 polygons x 16 stripes = 1024 blocks, 256 threads each
    raster_fused<<<1024, 256, 0, stream>>>(poly, out);
}

// Round 4
// 12.391 us; speedup vs baseline: 3.8414x; 1.2585x over previous
//
#include <hip/hip_runtime.h>
#include <hip/hip_bf16.h>
#include <math.h>

// out[p][i][j] = sigmoid(C * D / 512), p<64, i,j<256
//   x[k] = polygons[p][k][1]*256 (compared against px=i)
//   y[k] = polygons[p][k][0]*256 (compared against py=j)
//
// Block = (p, 16-row stripe), thread = column j.
// Phase 1: cooperative D-field on a 4px grid (5 rows x 65 cols) -> LDS.
//          (cuts the 8-sqrt-per-pixel trans load by ~12x; bilinear error
//           <= ~7 units of D worst-case vs ~39-unit tolerance)
// Mask:    exact even-odd parity per (j, 16 rows) with IEEE reference math
//          (bit-identical to the passing round-2/3 kernels).
// Phase 2: bilinear interp of D + Pade(5,4) tanh sigmoid (1 rcp, no exp).

#define LOAD_VERTS(poly_p)                                         \
    const float4* v4 = (const float4*)(poly_p);                    \
    float4 q0 = v4[0], q1 = v4[1], q2 = v4[2], q3 = v4[3];         \
    float x[8], y[8];                                              \
    y[0] = q0.x * 256.0f; x[0] = q0.y * 256.0f;                    \
    y[1] = q0.z * 256.0f; x[1] = q0.w * 256.0f;                    \
    y[2] = q1.x * 256.0f; x[2] = q1.y * 256.0f;                    \
    y[3] = q1.z * 256.0f; x[3] = q1.w * 256.0f;                    \
    y[4] = q2.x * 256.0f; x[4] = q2.y * 256.0f;                    \
    y[5] = q2.z * 256.0f; x[5] = q2.w * 256.0f;                    \
    y[6] = q3.x * 256.0f; x[6] = q3.y * 256.0f;                    \
    y[7] = q3.z * 256.0f; x[7] = q3.w * 256.0f;

__global__ __launch_bounds__(256)
void raster_fused(const float* __restrict__ poly, float* __restrict__ out) {
    __shared__ float Dg[5 * 65];     // rows i0+4*gr (gr=0..4), cols 4*gc (gc=0..64)

    int bid = blockIdx.x;
    int p  = bid >> 4;            // polygon
    int i0 = (bid & 15) << 4;     // stripe start row
    int j  = threadIdx.x;         // column
    float py = (float)j;
    LOAD_VERTS(poly + (size_t)p * 16)

    // ---- phase 1: coarse distance field into LDS ----
    for (int q = threadIdx.x; q < 325; q += 256) {
        int gr = q / 65;              // 0..4
        int gc = q - gr * 65;         // 0..64
        float gi = (float)(i0 + (gr << 2));   // row coord (may be 256: virtual)
        float gj = (float)(gc << 2);          // col coord
        float s = 0.0f;
        #pragma unroll
        for (int k = 0; k < 8; ++k) {
            float dx = x[k] - gi;
            float dy = y[k] - gj;
            s += __builtin_amdgcn_sqrtf(fmaf(dx, dx, dy * dy));
        }
        Dg[q] = s;
    }

    // ---- exact parity mask for rows [i0, i0+16) (IEEE, reference order) ----
    unsigned int mask = 0;
    #pragma unroll
    for (int k = 0; k < 8; ++k) {
        int kn = (k + 1) & 7;
        bool cond = (y[k] > py) != (y[kn] > py);
        if (cond) {
            float denom = y[kn] - y[k];                               // nonzero when cond
            float xint  = (x[kn] - x[k]) * (py - y[k]) / denom + x[k]; // IEEE, ref order
            int m;
            if (!(xint > 0.0f))       m = 0;
            else if (xint > 255.0f)   m = 256;
            else                      m = (int)ceilf(xint);
            int r = m - i0;
            unsigned int ones = (r <= 0) ? 0u
                              : (r >= 16) ? 0xffffu
                              : ((1u << r) - 1u);
            mask ^= ones;
        }
    }

    __syncthreads();

    // ---- phase 2: bilinear interp + Pade sigmoid ----
    int   gc = j >> 2;
    float u  = (float)(j & 3) * 0.25f;
    float* op = out + ((((size_t)p << 8) + i0) << 8) + j;

    #pragma unroll
    for (int r = 0; r < 16; ++r) {
        int   gr = r >> 2;
        float t  = (float)(r & 3) * 0.25f;
        float d00 = Dg[gr * 65 + gc],       d01 = Dg[gr * 65 + gc + 1];
        float d10 = Dg[(gr + 1) * 65 + gc], d11 = Dg[(gr + 1) * 65 + gc + 1];
        float a = fmaf(u, d01 - d00, d00);
        float b = fmaf(u, d11 - d10, d10);
        float D = fmaf(t, b - a, a);

        float C  = ((mask >> r) & 1) ? 1.0f : -1.0f;
        // sigmoid(z) = 0.5 + 0.5*tanh(z/2), z = C*D/512 -> th = C*D/1024, |th|<=2.84
        float th = C * D * (1.0f / 1024.0f);
        float t2 = th * th;
        float t4 = t2 * t2;
        float num = th * (t4 + fmaf(105.0f, t2, 945.0f));
        float den = fmaf(15.0f, t4, fmaf(420.0f, t2, 945.0f));
        float sig = fmaf(0.5f * num, __builtin_amdgcn_rcpf(den), 0.5f);
        op[(size_t)r << 8] = sig;
    }
}

extern "C" void kernel_launch(void* const* d_in, const int* in_sizes, int n_in,
                              void* d_out, int out_size, void* d_ws, size_t ws_size,
                              hipStream_t stream) {
    const float* poly = (const float*)d_in[0];
    float* out = (float*)d_out;
    // 64 polygons x 16 stripes = 1024 blocks, 256 threads each
    raster_fused<<<1024, 256, 0, stream>>>(poly, out);
}

// Round 5
// 11.633 us; speedup vs baseline: 4.0914x; 1.0651x over previous
//
#include <hip/hip_runtime.h>
#include <hip/hip_bf16.h>
#include <math.h>

// out[p][i][j] = sigmoid(C * D / 512), p<64, i,j<256
//   x[k] = polygons[p][k][1]*256 (compared against px=i)
//   y[k] = polygons[p][k][0]*256 (compared against py=j)
//
// Block = (p, 16-row stripe), thread = column j.
// Phase 1: cooperative S+ = sigmoid(+D/512) on a 4-px grid (5 x 65) -> LDS.
//          S+ is smooth everywhere (sign flip handled after interpolation
//          via sigmoid(-z) = 1 - sigmoid(z)), so bilinear interp error is
//          bounded by the same ~<=3-unit D-grid error * max slope 0.25/512
//          that already passed in round 4.
// Mask:    exact even-odd parity per (j, 16 rows), IEEE reference math
//          (bit-identical to rounds 2-4).
// Phase 2: bilinear interp + conditional (1 - s). Zero transcendental ops.

#define LOAD_VERTS(poly_p)                                         \
    const float4* v4 = (const float4*)(poly_p);                    \
    float4 q0 = v4[0], q1 = v4[1], q2 = v4[2], q3 = v4[3];         \
    float x[8], y[8];                                              \
    y[0] = q0.x * 256.0f; x[0] = q0.y * 256.0f;                    \
    y[1] = q0.z * 256.0f; x[1] = q0.w * 256.0f;                    \
    y[2] = q1.x * 256.0f; x[2] = q1.y * 256.0f;                    \
    y[3] = q1.z * 256.0f; x[3] = q1.w * 256.0f;                    \
    y[4] = q2.x * 256.0f; x[4] = q2.y * 256.0f;                    \
    y[5] = q2.z * 256.0f; x[5] = q2.w * 256.0f;                    \
    y[6] = q3.x * 256.0f; x[6] = q3.y * 256.0f;                    \
    y[7] = q3.z * 256.0f; x[7] = q3.w * 256.0f;

__global__ __launch_bounds__(256)
void raster_fused(const float* __restrict__ poly, float* __restrict__ out) {
    __shared__ float Sg[5 * 65];   // S+ at rows i0+4*gr, cols 4*gc

    int bid = blockIdx.x;
    int p  = bid >> 4;            // polygon
    int i0 = (bid & 15) << 4;     // stripe start row
    int j  = threadIdx.x;         // column
    float py = (float)j;
    LOAD_VERTS(poly + (size_t)p * 16)

    // ---- phase 1: S+ = sigmoid(D/512) on the coarse grid ----
    for (int q = threadIdx.x; q < 325; q += 256) {
        int gr = q / 65;
        int gc = q - gr * 65;
        float gi = (float)(i0 + (gr << 2));
        float gj = (float)(gc << 2);
        float s = 0.0f;
        #pragma unroll
        for (int k = 0; k < 8; ++k) {
            float dx = x[k] - gi;
            float dy = y[k] - gj;
            s += __builtin_amdgcn_sqrtf(fmaf(dx, dx, dy * dy));
        }
        float e = __expf(-s * (1.0f / 512.0f));
        Sg[q] = __builtin_amdgcn_rcpf(1.0f + e);
    }

    // ---- exact parity mask for rows [i0, i0+16) (IEEE, reference order) ----
    unsigned int mask = 0;
    #pragma unroll
    for (int k = 0; k < 8; ++k) {
        int kn = (k + 1) & 7;
        bool cond = (y[k] > py) != (y[kn] > py);
        if (cond) {
            float denom = y[kn] - y[k];                                // nonzero when cond
            float xint  = (x[kn] - x[k]) * (py - y[k]) / denom + x[k]; // IEEE, ref order
            int m;
            if (!(xint > 0.0f))       m = 0;
            else if (xint > 255.0f)   m = 256;
            else                      m = (int)ceilf(xint);
            int r = m - i0;
            unsigned int ones = (r <= 0) ? 0u
                              : (r >= 16) ? 0xffffu
                              : ((1u << r) - 1u);
            mask ^= ones;
        }
    }

    __syncthreads();

    // ---- phase 2: bilinear interp + sign flip; zero trans ops ----
    int   gc = j >> 2;
    float u  = (float)(j & 3) * 0.25f;

    // interpolate along u for the 5 grid rows this thread needs
    float A[5];
    #pragma unroll
    for (int gr = 0; gr < 5; ++gr) {
        float s0 = Sg[gr * 65 + gc];
        float s1 = Sg[gr * 65 + gc + 1];
        A[gr] = fmaf(u, s1 - s0, s0);
    }

    float* op = out + ((((size_t)p << 8) + i0) << 8) + j;
    #pragma unroll
    for (int r = 0; r < 16; ++r) {
        int   gr = r >> 2;
        float t  = (float)(r & 3) * 0.25f;
        float sp = fmaf(t, A[gr + 1] - A[gr], A[gr]);   // sigmoid(+D/512)
        float sv = ((mask >> r) & 1) ? sp : 1.0f - sp;
        op[(size_t)r << 8] = sv;
    }
}

extern "C" void kernel_launch(void* const* d_in, const int* in_sizes, int n_in,
                              void* d_out, int out_size, void* d_ws, size_t ws_size,
                              hipStream_t stream) {
    const float* poly = (const float*)d_in[0];
    float* out = (float*)d_out;
    raster_fused<<<1024, 256, 0, stream>>>(poly, out);
}